// Round 1
// baseline (219.212 us; speedup 1.0000x reference)
//
#include <hip/hip_runtime.h>

// VariableSelectionNetwork (TFT VSN) fused kernel for MI355X / gfx950.
// B=64 T=512 F=32 U=64, rows N = B*T = 32768.
// out = concat( out[N][64], w[N][32] ) in f32.

typedef float f4      __attribute__((ext_vector_type(4)));
typedef float f32x4   __attribute__((ext_vector_type(4)));
typedef short bf16x8  __attribute__((ext_vector_type(8)));

#define N_ROWS 32768
#define F_DIM  32
#define U_DIM  64
#define RPB    128          // rows per block
#define NTHR   512          // 8 waves
#define NBLK   (N_ROWS / RPB)

// ---- LDS byte offsets (total 123904 B) ----
#define X_OFF   0           // float [128][36]   x tile (padded)
#define WT_OFF  18432       // float [128][33]   softmax weights tile
#define WB_OFF  35328       // ushort [2][3][64*64]  bf16 transposed W2/Wg1/Wg2 (dbuf, swizzled)
#define VB_OFF  84480       // float  [2][9][64]     per-f vectors (dbuf)
#define H2_OFF  89088       // float  [8][16][68]    per-wave h2 scratch
#define SMEM_BYTES 123904

__device__ __forceinline__ unsigned short f2bf(float x) {
  union { float f; unsigned u; } c; c.f = x;
  unsigned r = (c.u + 0x7FFFu + ((c.u >> 16) & 1u)) >> 16;
  return (unsigned short)r;
}

// =====================================================================
// prep: transpose W2/Wg1/Wg2 -> bf16 [m][f][v][u] in ws; pack 9 vec tables
// =====================================================================
__global__ __launch_bounds__(256) void vsn_prep(
    const float* __restrict__ W2,  const float* __restrict__ Wg1, const float* __restrict__ Wg2,
    const float* __restrict__ W1,  const float* __restrict__ b1,  const float* __restrict__ b2,
    const float* __restrict__ bg1, const float* __restrict__ bg2,
    const float* __restrict__ Wp,  const float* __restrict__ bp,
    const float* __restrict__ gamma_, const float* __restrict__ beta_,
    unsigned short* __restrict__ wtg, float* __restrict__ vect)
{
  const int t = threadIdx.x, blk = blockIdx.x;
  if (blk < 96) {
    __shared__ float tile[64][65];
    const int m = blk >> 5, f = blk & 31;
    const float* src = (m == 0) ? W2 : (m == 1) ? Wg1 : Wg2;
    src += f * 4096;
    #pragma unroll
    for (int i = 0; i < 16; ++i) {
      int idx = t + i * 256;
      tile[idx >> 6][idx & 63] = src[idx];
    }
    __syncthreads();
    unsigned short* dst = wtg + (m * 32 + f) * 4096;
    #pragma unroll
    for (int i = 0; i < 16; ++i) {
      int idx = t + i * 256;                 // idx = v*64 + u
      dst[idx] = f2bf(tile[idx & 63][idx >> 6]);   // = W[f][u][v]
    }
  } else {
    // vec table: [f][a][64], a: 0 W1,1 b1,2 b2,3 bg1,4 bg2,5 Wp,6 bp,7 gamma,8 beta
    #pragma unroll
    for (int a = 0; a < 9; ++a) {
      const float* s = (a==0)?W1:(a==1)?b1:(a==2)?b2:(a==3)?bg1:(a==4)?bg2:
                       (a==5)?Wp:(a==6)?bp:(a==7)?gamma_:beta_;
      for (int i = t; i < 2048; i += 256)
        vect[(i >> 6) * 576 + a * 64 + (i & 63)] = s[i];
    }
  }
}

// =====================================================================
// main fused kernel
// =====================================================================
__global__ __launch_bounds__(NTHR, 2) void vsn_main(
    const float* __restrict__ x,
    const unsigned short* __restrict__ wtg,   // [3][32][64][64] bf16, [v][u]
    const float* __restrict__ vect,           // [32][9][64]
    const float* __restrict__ w1w, const float* __restrict__ w2w,
    const float* __restrict__ wg1w, const float* __restrict__ wg2w,
    const float* __restrict__ b1w, const float* __restrict__ b2w,
    const float* __restrict__ bg1w, const float* __restrict__ bg2w,
    const float* __restrict__ gammaw, const float* __restrict__ betaw,
    float* __restrict__ out, float* __restrict__ wout)
{
  __shared__ __align__(16) char smem[SMEM_BYTES];
  const int t  = threadIdx.x;
  const int r0 = blockIdx.x * RPB;

  float* xt  = (float*)(smem + X_OFF);
  float* wtl = (float*)(smem + WT_OFF);
  unsigned short* wbuf = (unsigned short*)(smem + WB_OFF);
  float* vbuf = (float*)(smem + VB_OFF);
  float* h2b  = (float*)(smem + H2_OFF);
  // phase-A overlays
  float* wAl = (float*)(smem + WB_OFF);            // [4][32][32] f32
  float* vAl = (float*)(smem + WB_OFF + 16384);    // [6][32] f32
  float* hex = (float*)(smem + H2_OFF);            // [128][36] f32

  // ---- stage x tile (coalesced f32x4) ----
  #pragma unroll
  for (int i = 0; i < 2; ++i) {
    int i4 = t + i * NTHR;                   // 0..1023
    f4 v = ((const f4*)(x + (size_t)r0 * F_DIM))[i4];
    *((f4*)(xt + (i4 >> 3) * 36 + ((i4 & 7) << 2))) = v;
  }

  // ---- prefetch f=0 phase-B weights into regs (held through phase A) ----
  int4 pw0, pw1, pw2; f4 pv0;
  {
    const int4* wt4 = (const int4*)wtg;      // 512 int4 per (m,f)
    pw0 = wt4[(0 * 32 + 0) * 512 + t];
    pw1 = wt4[(1 * 32 + 0) * 512 + t];
    pw2 = wt4[(2 * 32 + 0) * 512 + t];
    if (t < 144) pv0 = ((const f4*)(vect))[t];
  }

  // ---- stage phase-A weights ----
  #pragma unroll
  for (int i = 0; i < 2; ++i) {
    int i4 = t + i * NTHR;                   // 0..1023
    int m = i4 >> 8, off = (i4 & 255) << 2;
    const float* src = (m == 0) ? w1w : (m == 1) ? w2w : (m == 2) ? wg1w : wg2w;
    *(f4*)(wAl + m * 1024 + off) = *((const f4*)(src + off));
  }
  if (t < 48) {
    int m = t >> 3, off = (t & 7) << 2;
    const float* src = (m==0)?b1w:(m==1)?b2w:(m==2)?bg1w:(m==3)?bg2w:(m==4)?gammaw:betaw;
    *(f4*)(vAl + m * 32 + off) = *((const f4*)(src + off));
  }
  __syncthreads();

  // ================= PHASE A : weights GRN + softmax =================
  {
    const int ar = t >> 2;        // row 0..127
    const int g0 = (t & 3) << 3;  // this thread's 8 output columns

    // stage 1: h1 = elu(x @ w1w + b1w)
    float hacc[8];
    #pragma unroll
    for (int j = 0; j < 8; ++j) hacc[j] = vAl[0 * 32 + g0 + j];
    #pragma unroll
    for (int ff = 0; ff < 32; ++ff) {
      float xv = xt[ar * 36 + ff];
      f4 w0 = *(const f4*)(wAl + 0 * 1024 + ff * 32 + g0);
      f4 w1 = *(const f4*)(wAl + 0 * 1024 + ff * 32 + g0 + 4);
      #pragma unroll
      for (int j = 0; j < 4; ++j) { hacc[j] += xv * w0[j]; hacc[4 + j] += xv * w1[j]; }
    }
    #pragma unroll
    for (int j = 0; j < 8; ++j) { float z = hacc[j]; hacc[j] = z > 0.f ? z : (__expf(z) - 1.f); }
    *(f4*)(hex + ar * 36 + g0)     = (f4){hacc[0], hacc[1], hacc[2], hacc[3]};
    *(f4*)(hex + ar * 36 + g0 + 4) = (f4){hacc[4], hacc[5], hacc[6], hacc[7]};
    __syncthreads();

    // stage 2: h2 = h1 @ w2w + b2w
    float h2acc[8];
    #pragma unroll
    for (int j = 0; j < 8; ++j) h2acc[j] = vAl[1 * 32 + g0 + j];
    #pragma unroll
    for (int ff = 0; ff < 32; ++ff) {
      float hv = hex[ar * 36 + ff];
      f4 w0 = *(const f4*)(wAl + 1 * 1024 + ff * 32 + g0);
      f4 w1 = *(const f4*)(wAl + 1 * 1024 + ff * 32 + g0 + 4);
      #pragma unroll
      for (int j = 0; j < 4; ++j) { h2acc[j] += hv * w0[j]; h2acc[4 + j] += hv * w1[j]; }
    }
    __syncthreads();   // everyone done reading h1 from hex
    *(f4*)(hex + ar * 36 + g0)     = (f4){h2acc[0], h2acc[1], h2acc[2], h2acc[3]};
    *(f4*)(hex + ar * 36 + g0 + 4) = (f4){h2acc[4], h2acc[5], h2acc[6], h2acc[7]};
    __syncthreads();

    // stage 3: GLU
    float aacc[8], bacc[8];
    #pragma unroll
    for (int j = 0; j < 8; ++j) { aacc[j] = vAl[2 * 32 + g0 + j]; bacc[j] = vAl[3 * 32 + g0 + j]; }
    #pragma unroll
    for (int ff = 0; ff < 32; ++ff) {
      float hv = hex[ar * 36 + ff];
      f4 wa0 = *(const f4*)(wAl + 2 * 1024 + ff * 32 + g0);
      f4 wa1 = *(const f4*)(wAl + 2 * 1024 + ff * 32 + g0 + 4);
      f4 wb0 = *(const f4*)(wAl + 3 * 1024 + ff * 32 + g0);
      f4 wb1 = *(const f4*)(wAl + 3 * 1024 + ff * 32 + g0 + 4);
      #pragma unroll
      for (int j = 0; j < 4; ++j) {
        aacc[j] += hv * wa0[j]; aacc[4 + j] += hv * wa1[j];
        bacc[j] += hv * wb0[j]; bacc[4 + j] += hv * wb1[j];
      }
    }
    float zz[8];
    #pragma unroll
    for (int j = 0; j < 8; ++j) {
      float sg = __builtin_amdgcn_rcpf(1.f + __expf(-bacc[j]));
      zz[j] = aacc[j] * sg + xt[ar * 36 + g0 + j];    // GLU + residual
    }
    __syncthreads();   // done reading h2 from hex
    *(f4*)(hex + ar * 36 + g0)     = (f4){zz[0], zz[1], zz[2], zz[3]};
    *(f4*)(hex + ar * 36 + g0 + 4) = (f4){zz[4], zz[5], zz[6], zz[7]};
    __syncthreads();

    // LN + softmax over F=32 (each thread redundantly reduces its row from LDS)
    float s1 = 0.f, s2 = 0.f;
    #pragma unroll
    for (int ff = 0; ff < 32; ++ff) { float z = hex[ar * 36 + ff]; s1 += z; s2 += z * z; }
    float mA = s1 * 0.03125f;
    float vA = s2 * 0.03125f - mA * mA;
    float rsA = __builtin_amdgcn_rsqf(vA + 1e-3f);
    float mx = -1e30f;
    #pragma unroll
    for (int ff = 0; ff < 32; ++ff) {
      float y = (hex[ar * 36 + ff] - mA) * rsA * vAl[4 * 32 + ff] + vAl[5 * 32 + ff];
      mx = fmaxf(mx, y);
    }
    float es = 0.f;
    #pragma unroll
    for (int ff = 0; ff < 32; ++ff) {
      float y = (hex[ar * 36 + ff] - mA) * rsA * vAl[4 * 32 + ff] + vAl[5 * 32 + ff];
      es += __expf(y - mx);
    }
    float inv = __builtin_amdgcn_rcpf(es);
    float wv8[8];
    #pragma unroll
    for (int j = 0; j < 8; ++j) {
      float y = (hex[ar * 36 + g0 + j] - mA) * rsA * vAl[4 * 32 + g0 + j] + vAl[5 * 32 + g0 + j];
      wv8[j] = __expf(y - mx) * inv;
      wtl[ar * 33 + g0 + j] = wv8[j];
    }
    *(f4*)(wout + (size_t)(r0 + ar) * 32 + g0)     = (f4){wv8[0], wv8[1], wv8[2], wv8[3]};
    *(f4*)(wout + (size_t)(r0 + ar) * 32 + g0 + 4) = (f4){wv8[4], wv8[5], wv8[6], wv8[7]};
    __syncthreads();   // phase A done; wAl/hex regions are now free
  }

  // ---- write f=0 phase-B weights (swizzled) ----
  {
    const int bo = t * 16;
    const int sw = bo ^ (((t >> 3) & 7) << 4);   // v = bo>>7 = t>>3
    char* wb0 = (char*)wbuf;
    *(int4*)(wb0 + 0 * 8192 + sw) = pw0;
    *(int4*)(wb0 + 1 * 8192 + sw) = pw1;
    *(int4*)(wb0 + 2 * 8192 + sw) = pw2;
    if (t < 144) *(f4*)(vbuf + t * 4) = pv0;
  }
  __syncthreads();

  // ================= PHASE B : per-feature GRNs (MFMA) =================
  const int wid = t >> 6;          // wave 0..7  (16 rows each)
  const int lr  = t & 15;          // A-row / B-col base
  const int lg  = (t >> 4) & 3;    // quarter-group
  float* h2w = h2b + wid * (16 * 68);   // wave-private [16][68] f32

  f32x4 acc[4];
  #pragma unroll
  for (int nt = 0; nt < 4; ++nt) acc[nt] = (f32x4){0.f, 0.f, 0.f, 0.f};

  int cur = 0;
  for (int f = 0; f < F_DIM; ++f) {
    // prefetch f+1 weights into regs
    int4 qw0, qw1, qw2; f4 qv;
    if (f < 31) {
      const int4* wt4 = (const int4*)wtg;
      qw0 = wt4[(0 * 32 + f + 1) * 512 + t];
      qw1 = wt4[(1 * 32 + f + 1) * 512 + t];
      qw2 = wt4[(2 * 32 + f + 1) * 512 + t];
      if (t < 144) qv = ((const f4*)(vect + (f + 1) * 576))[t];
    }

    const char*  wbc = (const char*)wbuf + cur * 24576;
    const float* vbc = vbuf + cur * 576;

    // ---- h1 A-fragments, built in registers (rank-1 + ELU) ----
    const float s_ = xt[(wid * 16 + lr) * 36 + f];
    bf16x8 afr[2];
    #pragma unroll
    for (int kt = 0; kt < 2; ++kt) {
      const int u0 = 8 * lg + 32 * kt;
      f4 wa  = *(const f4*)(vbc + u0);
      f4 wb_ = *(const f4*)(vbc + u0 + 4);
      f4 ba  = *(const f4*)(vbc + 64 + u0);
      f4 bb_ = *(const f4*)(vbc + 64 + u0 + 4);
      bf16x8 af;
      #pragma unroll
      for (int j = 0; j < 4; ++j) {
        float h = s_ * wa[j] + ba[j];
        h = h > 0.f ? h : (__expf(h) - 1.f);
        af[j] = (short)f2bf(h);
      }
      #pragma unroll
      for (int j = 0; j < 4; ++j) {
        float h = s_ * wb_[j] + bb_[j];
        h = h > 0.f ? h : (__expf(h) - 1.f);
        af[4 + j] = (short)f2bf(h);
      }
      afr[kt] = af;
    }

    // ---- GEMM1: h2 = h1 @ W2 ----
    f32x4 c1[4];
    #pragma unroll
    for (int nt = 0; nt < 4; ++nt) {
      c1[nt] = (f32x4){0.f, 0.f, 0.f, 0.f};
      const int v_ = lr + 16 * nt;
      #pragma unroll
      for (int kt = 0; kt < 2; ++kt) {
        int bo = (v_ << 7) + ((8 * lg + 32 * kt) << 1);
        bo ^= (v_ & 7) << 4;
        bf16x8 bfr = *(const bf16x8*)(wbc + 0 * 8192 + bo);
        c1[nt] = __builtin_amdgcn_mfma_f32_16x16x32_bf16(afr[kt], bfr, c1[nt], 0, 0, 0);
      }
    }

    // ---- h2 (+b2) -> wave-private LDS ----
    #pragma unroll
    for (int nt = 0; nt < 4; ++nt) {
      const float b2v = vbc[2 * 64 + lr + 16 * nt];
      #pragma unroll
      for (int rg = 0; rg < 4; ++rg)
        h2w[(4 * lg + rg) * 68 + lr + 16 * nt] = c1[nt][rg] + b2v;
    }
    asm volatile("s_waitcnt lgkmcnt(0)" ::: "memory");

    // ---- A2 fragments from LDS (f32 -> bf16) ----
    bf16x8 a2[2];
    #pragma unroll
    for (int kt = 0; kt < 2; ++kt) {
      const int u0 = 8 * lg + 32 * kt;
      f4 p0 = *(const f4*)(h2w + lr * 68 + u0);
      f4 p1 = *(const f4*)(h2w + lr * 68 + u0 + 4);
      bf16x8 af;
      #pragma unroll
      for (int j = 0; j < 4; ++j) { af[j] = (short)f2bf(p0[j]); af[4 + j] = (short)f2bf(p1[j]); }
      a2[kt] = af;
    }

    // ---- GEMM2a / GEMM2b ----
    f32x4 ca[4], cb[4];
    #pragma unroll
    for (int nt = 0; nt < 4; ++nt) { ca[nt] = (f32x4){0.f,0.f,0.f,0.f}; cb[nt] = (f32x4){0.f,0.f,0.f,0.f}; }
    #pragma unroll
    for (int nt = 0; nt < 4; ++nt) {
      const int v_ = lr + 16 * nt;
      #pragma unroll
      for (int kt = 0; kt < 2; ++kt) {
        int bo = (v_ << 7) + ((8 * lg + 32 * kt) << 1);
        bo ^= (v_ & 7) << 4;
        bf16x8 b1f = *(const bf16x8*)(wbc + 1 * 8192 + bo);
        bf16x8 b2f = *(const bf16x8*)(wbc + 2 * 8192 + bo);
        ca[nt] = __builtin_amdgcn_mfma_f32_16x16x32_bf16(a2[kt], b1f, ca[nt], 0, 0, 0);
        cb[nt] = __builtin_amdgcn_mfma_f32_16x16x32_bf16(a2[kt], b2f, cb[nt], 0, 0, 0);
      }
    }

    // ---- epilogue: GLU + residual + LN + weighted accumulate ----
    float xr[4], wr[4];
    #pragma unroll
    for (int rg = 0; rg < 4; ++rg) {
      const int rl = wid * 16 + 4 * lg + rg;
      xr[rg] = xt[rl * 36 + f];
      wr[rg] = wtl[rl * 33 + f];
    }
    float zf[4][4];
    float s1[4] = {0.f,0.f,0.f,0.f}, s2[4] = {0.f,0.f,0.f,0.f};
    #pragma unroll
    for (int nt = 0; nt < 4; ++nt) {
      const int u = lr + 16 * nt;
      const float bg1v = vbc[3 * 64 + u], bg2v = vbc[4 * 64 + u];
      const float wpv  = vbc[5 * 64 + u], bpv  = vbc[6 * 64 + u];
      #pragma unroll
      for (int rg = 0; rg < 4; ++rg) {
        float a = ca[nt][rg] + bg1v;
        float b = cb[nt][rg] + bg2v;
        float sg = __builtin_amdgcn_rcpf(1.f + __expf(-b));
        float z = a * sg + (xr[rg] * wpv + bpv);
        zf[nt][rg] = z;
        s1[rg] += z;
        s2[rg] += z * z;
      }
    }
    #pragma unroll
    for (int rg = 0; rg < 4; ++rg) {
      #pragma unroll
      for (int m = 1; m < 16; m <<= 1) {
        s1[rg] += __shfl_xor(s1[rg], m, 64);
        s2[rg] += __shfl_xor(s2[rg], m, 64);
      }
    }
    float mn[4], rs[4];
    #pragma unroll
    for (int rg = 0; rg < 4; ++rg) {
      mn[rg] = s1[rg] * 0.015625f;
      float var = s2[rg] * 0.015625f - mn[rg] * mn[rg];
      rs[rg] = __builtin_amdgcn_rsqf(var + 1e-3f);
    }
    #pragma unroll
    for (int nt = 0; nt < 4; ++nt) {
      const int u = lr + 16 * nt;
      const float gav = vbc[7 * 64 + u], bev = vbc[8 * 64 + u];
      #pragma unroll
      for (int rg = 0; rg < 4; ++rg) {
        float y = (zf[nt][rg] - mn[rg]) * rs[rg] * gav + bev;
        acc[nt][rg] += y * wr[rg];
      }
    }

    // ---- stage f+1 weights into the other buffer ----
    if (f < 31) {
      const int bo = t * 16;
      const int sw = bo ^ (((t >> 3) & 7) << 4);
      char* wbn = (char*)wbuf + (cur ^ 1) * 24576;
      *(int4*)(wbn + 0 * 8192 + sw) = qw0;
      *(int4*)(wbn + 1 * 8192 + sw) = qw1;
      *(int4*)(wbn + 2 * 8192 + sw) = qw2;
      if (t < 144) *(f4*)(vbuf + (cur ^ 1) * 576 + t * 4) = qv;
      cur ^= 1;
    }
    __syncthreads();
  }

  // ---- store out ----
  #pragma unroll
  for (int nt = 0; nt < 4; ++nt) {
    #pragma unroll
    for (int rg = 0; rg < 4; ++rg) {
      const int row = r0 + wid * 16 + 4 * lg + rg;
      out[(size_t)row * U_DIM + lr + 16 * nt] = acc[nt][rg];
    }
  }
}

// =====================================================================
extern "C" void kernel_launch(void* const* d_in, const int* in_sizes, int n_in,
                              void* d_out, int out_size, void* d_ws, size_t ws_size,
                              hipStream_t stream)
{
  (void)in_sizes; (void)n_in; (void)out_size; (void)ws_size;
  const float* x    = (const float*)d_in[0];
  const float* W1   = (const float*)d_in[1];
  const float* b1   = (const float*)d_in[2];
  const float* W2   = (const float*)d_in[3];
  const float* b2   = (const float*)d_in[4];
  const float* Wg1  = (const float*)d_in[5];
  const float* bg1  = (const float*)d_in[6];
  const float* Wg2  = (const float*)d_in[7];
  const float* bg2  = (const float*)d_in[8];
  const float* Wp   = (const float*)d_in[9];
  const float* bp   = (const float*)d_in[10];
  const float* gm   = (const float*)d_in[11];
  const float* bt   = (const float*)d_in[12];
  const float* w1w  = (const float*)d_in[13];
  const float* b1w  = (const float*)d_in[14];
  const float* w2w  = (const float*)d_in[15];
  const float* b2w  = (const float*)d_in[16];
  const float* wg1w = (const float*)d_in[17];
  const float* bg1w = (const float*)d_in[18];
  const float* wg2w = (const float*)d_in[19];
  const float* bg2w = (const float*)d_in[20];
  const float* gmw  = (const float*)d_in[21];
  const float* btw  = (const float*)d_in[22];

  unsigned short* wtg = (unsigned short*)d_ws;             // 786432 B
  float* vect = (float*)((char*)d_ws + 786432);            // 73728 B

  float* out  = (float*)d_out;
  float* wout = out + (size_t)N_ROWS * U_DIM;

  vsn_prep<<<97, 256, 0, stream>>>(W2, Wg1, Wg2, W1, b1, b2, bg1, bg2, Wp, bp, gm, bt, wtg, vect);
  vsn_main<<<NBLK, NTHR, 0, stream>>>(x, wtg, vect, w1w, w2w, wg1w, wg2w,
                                      b1w, b2w, bg1w, bg2w, gmw, btw, out, wout);
}